// Round 1
// baseline (105.430 us; speedup 1.0000x reference)
//
#include <hip/hip_runtime.h>
#include <hip/hip_bf16.h>
#include <float.h>

// Problem constants (from reference): B=16, M=4096.
#define NB 16
#define MPTS 4096
#define BLK 256           // threads per block
#define CHUNKS_PER_B (MPTS / BLK)   // 16 blocks per batch item
#define UNROLL 8

// Main kernel: one block = (batch b, chunk of 256 pred points).
// LDS holds all 4096 gt points (float4 -> 64 KB). Inner loop over gt points
// is wave-uniform -> ds_read_b128 broadcast (conflict-free).
__global__ __launch_bounds__(BLK) void adds_main(
    const float* __restrict__ pred_R, const float* __restrict__ pred_t,
    const float* __restrict__ gt_R,   const float* __restrict__ gt_t,
    const float* __restrict__ mp,     float* __restrict__ partial)
{
    __shared__ float4 gpts[MPTS];          // 64 KB
    __shared__ float  wsum[BLK / 64];

    const int b   = blockIdx.x >> 4;       // /CHUNKS_PER_B
    const int mb  = (blockIdx.x & 15) << 8;
    const int tid = threadIdx.x;

    // gt transform for this batch
    float gR[9];
#pragma unroll
    for (int i = 0; i < 9; ++i) gR[i] = gt_R[b * 9 + i];
    const float gtx = gt_t[b * 3 + 0];
    const float gty = gt_t[b * 3 + 1];
    const float gtz = gt_t[b * 3 + 2];

    // Fill LDS with transformed gt points (cooperative, 16 per thread)
    for (int n = tid; n < MPTS; n += BLK) {
        const float mx = mp[n * 3 + 0];
        const float my = mp[n * 3 + 1];
        const float mz = mp[n * 3 + 2];
        // g[j] = sum_k R[j,k]*m[k] + t[j]
        const float gx = fmaf(gR[0], mx, fmaf(gR[1], my, fmaf(gR[2], mz, gtx)));
        const float gy = fmaf(gR[3], mx, fmaf(gR[4], my, fmaf(gR[5], mz, gty)));
        const float gz = fmaf(gR[6], mx, fmaf(gR[7], my, fmaf(gR[8], mz, gtz)));
        gpts[n] = make_float4(gx, gy, gz, 0.0f);
    }

    // This thread's pred point
    float pR[9];
#pragma unroll
    for (int i = 0; i < 9; ++i) pR[i] = pred_R[b * 9 + i];
    const float ptx = pred_t[b * 3 + 0];
    const float pty = pred_t[b * 3 + 1];
    const float ptz = pred_t[b * 3 + 2];

    const int m = mb + tid;
    const float mx = mp[m * 3 + 0];
    const float my = mp[m * 3 + 1];
    const float mz = mp[m * 3 + 2];
    const float px = fmaf(pR[0], mx, fmaf(pR[1], my, fmaf(pR[2], mz, ptx)));
    const float py = fmaf(pR[3], mx, fmaf(pR[4], my, fmaf(pR[5], mz, pty)));
    const float pz = fmaf(pR[6], mx, fmaf(pR[7], my, fmaf(pR[8], mz, ptz)));

    __syncthreads();

    // Min over all gt points; UNROLL independent accumulators break the
    // v_min dependent chain.
    float best[UNROLL];
#pragma unroll
    for (int u = 0; u < UNROLL; ++u) best[u] = FLT_MAX;

    for (int n = 0; n < MPTS; n += UNROLL) {
#pragma unroll
        for (int u = 0; u < UNROLL; ++u) {
            const float4 g = gpts[n + u];
            const float dx = px - g.x;
            const float dy = py - g.y;
            const float dz = pz - g.z;
            const float d2 = fmaf(dx, dx, fmaf(dy, dy, dz * dz));
            best[u] = fminf(best[u], d2);
        }
    }

    float mind = best[0];
#pragma unroll
    for (int u = 1; u < UNROLL; ++u) mind = fminf(mind, best[u]);

    const float dist = sqrtf(fmaxf(mind, 0.0f));

    // Block-sum of dist -> partial[blockIdx.x]
    float v = dist;
#pragma unroll
    for (int off = 32; off > 0; off >>= 1) v += __shfl_down(v, off, 64);
    if ((tid & 63) == 0) wsum[tid >> 6] = v;
    __syncthreads();
    if (tid == 0) {
        float s = 0.0f;
#pragma unroll
        for (int w = 0; w < BLK / 64; ++w) s += wsum[w];
        partial[blockIdx.x] = s;
    }
}

// Final reduction: 256 partials -> scalar mean.
__global__ __launch_bounds__(256) void adds_reduce(
    const float* __restrict__ partial, float* __restrict__ out)
{
    __shared__ float wsum[4];
    const int tid = threadIdx.x;
    float v = partial[tid];
#pragma unroll
    for (int off = 32; off > 0; off >>= 1) v += __shfl_down(v, off, 64);
    if ((tid & 63) == 0) wsum[tid >> 6] = v;
    __syncthreads();
    if (tid == 0) {
        out[0] = (wsum[0] + wsum[1] + wsum[2] + wsum[3]) *
                 (1.0f / (float)(NB * MPTS));
    }
}

extern "C" void kernel_launch(void* const* d_in, const int* in_sizes, int n_in,
                              void* d_out, int out_size, void* d_ws, size_t ws_size,
                              hipStream_t stream) {
    const float* pred_R = (const float*)d_in[0];
    const float* pred_t = (const float*)d_in[1];
    const float* gt_R   = (const float*)d_in[2];
    const float* gt_t   = (const float*)d_in[3];
    const float* mp     = (const float*)d_in[4];
    float* out = (float*)d_out;
    float* partial = (float*)d_ws;   // 256 floats

    const int nblocks = NB * CHUNKS_PER_B;  // 256
    adds_main<<<dim3(nblocks), dim3(BLK), 0, stream>>>(
        pred_R, pred_t, gt_R, gt_t, mp, partial);
    adds_reduce<<<dim3(1), dim3(256), 0, stream>>>(partial, out);
}

// Round 2
// 67.731 us; speedup vs baseline: 1.5566x; 1.5566x over previous
//
#include <hip/hip_runtime.h>
#include <hip/hip_bf16.h>
#include <float.h>

// Problem constants: B=16, M=4096.
#define NB 16
#define MPTS 4096
#define NPRED (NB * MPTS)       // 65536 pred points total
#define GTQ 4                   // gt quarters (occupancy lever)
#define GTN (MPTS / GTQ)        // 1024 gt points per block
#define UNROLL 8

// Kernel 1: init per-pred-point min buffer to +inf (harness poisons ws once,
// and we must be idempotent across graph replays).
__global__ __launch_bounds__(1024) void adds_init(unsigned* __restrict__ dmin) {
    const int i = blockIdx.x * 1024 + threadIdx.x;
    dmin[i] = 0x7F800000u;      // +inf bits
}

// Kernel 2: one block = (batch b, 256-pred-point chunk, gt quarter).
// LDS holds the quarter's gt points as (-2gx,-2gy,-2gz,||g||^2) float4 (16 KB).
// score = <h.xyz, p> + h.w = ||g||^2 - 2 p.g ;  d2 = pn + min(score).
// Partial mins across quarters combined via atomicMin on float bits
// (valid because d2 is clamped >= 0; min is exact -> deterministic).
__global__ __launch_bounds__(256) void adds_main(
    const float* __restrict__ pred_R, const float* __restrict__ pred_t,
    const float* __restrict__ gt_R,   const float* __restrict__ gt_t,
    const float* __restrict__ mp,     unsigned* __restrict__ dmin)
{
    __shared__ float4 g4[GTN];          // 16 KB

    const int b   = blockIdx.x & 15;
    const int pch = (blockIdx.x >> 4) & 15;
    const int gtq = blockIdx.x >> 8;
    const int tid = threadIdx.x;

    // ---- stage gt quarter into LDS (transform fused) ----
    float gR[9];
#pragma unroll
    for (int i = 0; i < 9; ++i) gR[i] = gt_R[b * 9 + i];
    const float gtx = gt_t[b * 3 + 0];
    const float gty = gt_t[b * 3 + 1];
    const float gtz = gt_t[b * 3 + 2];

#pragma unroll
    for (int k = 0; k < GTN / 256; ++k) {
        const int nl = k * 256 + tid;          // local index in quarter
        const int n  = gtq * GTN + nl;         // global gt index
        const float mx = mp[n * 3 + 0];
        const float my = mp[n * 3 + 1];
        const float mz = mp[n * 3 + 2];
        const float gx = fmaf(gR[0], mx, fmaf(gR[1], my, fmaf(gR[2], mz, gtx)));
        const float gy = fmaf(gR[3], mx, fmaf(gR[4], my, fmaf(gR[5], mz, gty)));
        const float gz = fmaf(gR[6], mx, fmaf(gR[7], my, fmaf(gR[8], mz, gtz)));
        const float gn = fmaf(gx, gx, fmaf(gy, gy, gz * gz));
        g4[nl] = make_float4(-2.0f * gx, -2.0f * gy, -2.0f * gz, gn);
    }

    // ---- this thread's pred point ----
    float pR[9];
#pragma unroll
    for (int i = 0; i < 9; ++i) pR[i] = pred_R[b * 9 + i];
    const int m = pch * 256 + tid;
    const float mx = mp[m * 3 + 0];
    const float my = mp[m * 3 + 1];
    const float mz = mp[m * 3 + 2];
    const float px = fmaf(pR[0], mx, fmaf(pR[1], my, fmaf(pR[2], mz, pred_t[b * 3 + 0])));
    const float py = fmaf(pR[3], mx, fmaf(pR[4], my, fmaf(pR[5], mz, pred_t[b * 3 + 1])));
    const float pz = fmaf(pR[6], mx, fmaf(pR[7], my, fmaf(pR[8], mz, pred_t[b * 3 + 2])));
    const float pn = fmaf(px, px, fmaf(py, py, pz * pz));

    __syncthreads();

    // ---- min over the quarter: 4 VALU per gt point ----
    float best[UNROLL];
#pragma unroll
    for (int u = 0; u < UNROLL; ++u) best[u] = FLT_MAX;

    for (int n = 0; n < GTN; n += UNROLL) {
#pragma unroll
        for (int u = 0; u < UNROLL; ++u) {
            const float4 h = g4[n + u];
            const float s = fmaf(h.x, px, fmaf(h.y, py, fmaf(h.z, pz, h.w)));
            best[u] = fminf(best[u], s);
        }
    }

    float smin = best[0];
#pragma unroll
    for (int u = 1; u < UNROLL; ++u) smin = fminf(smin, best[u]);

    const float d2 = fmaxf(pn + smin, 0.0f);
    atomicMin(&dmin[b * MPTS + m], __float_as_uint(d2));
}

// Kernel 3: 65536 mins -> sqrt -> mean.
__global__ __launch_bounds__(1024) void adds_finish(
    const unsigned* __restrict__ dmin, float* __restrict__ out)
{
    __shared__ float wsum[16];
    const int tid = threadIdx.x;
    float s = 0.0f;
    for (int i = tid; i < NPRED; i += 1024)
        s += sqrtf(__uint_as_float(dmin[i]));
#pragma unroll
    for (int off = 32; off > 0; off >>= 1) s += __shfl_down(s, off, 64);
    if ((tid & 63) == 0) wsum[tid >> 6] = s;
    __syncthreads();
    if (tid == 0) {
        float t = 0.0f;
#pragma unroll
        for (int w = 0; w < 16; ++w) t += wsum[w];
        out[0] = t * (1.0f / (float)NPRED);
    }
}

extern "C" void kernel_launch(void* const* d_in, const int* in_sizes, int n_in,
                              void* d_out, int out_size, void* d_ws, size_t ws_size,
                              hipStream_t stream) {
    const float* pred_R = (const float*)d_in[0];
    const float* pred_t = (const float*)d_in[1];
    const float* gt_R   = (const float*)d_in[2];
    const float* gt_t   = (const float*)d_in[3];
    const float* mp     = (const float*)d_in[4];
    float* out = (float*)d_out;
    unsigned* dmin = (unsigned*)d_ws;       // 65536 * 4 B = 256 KB

    adds_init<<<dim3(NPRED / 1024), dim3(1024), 0, stream>>>(dmin);
    adds_main<<<dim3(NB * 16 * GTQ), dim3(256), 0, stream>>>(
        pred_R, pred_t, gt_R, gt_t, mp, dmin);
    adds_finish<<<dim3(1), dim3(1024), 0, stream>>>(dmin, out);
}

// Round 3
// 34.546 us; speedup vs baseline: 3.0519x; 1.9606x over previous
//
#include <hip/hip_runtime.h>
#include <hip/hip_bf16.h>
#include <float.h>

// Problem constants: B=16, M=4096.
#define NB 16
#define MPTS 4096
#define NPRED (NB * MPTS)       // 65536 pred points total
#define GTQ 8                   // gt partitions
#define GTN (MPTS / GTQ)        // 512 gt points per block
#define P 4                     // pred points per thread
#define BLK 256
#define PREDS_PER_BLK (BLK * P) // 1024
#define PCH (MPTS / PREDS_PER_BLK) // 4 pred chunks per batch

// Kernel 1: init per-pred-point min buffer to +inf.
__global__ __launch_bounds__(1024) void adds_init(unsigned* __restrict__ dmin) {
    const int i = blockIdx.x * 1024 + threadIdx.x;
    dmin[i] = 0x7F800000u;      // +inf bits
}

// Kernel 2: one block = (batch b, 1024-pred chunk, gt eighth).
// LDS: (-2gx,-2gy,-2gz,||g||^2) float4 per gt point (8 KB).
// Each thread owns P=4 pred points -> each ds_read_b128 feeds 16 FMA-chains.
__global__ __launch_bounds__(BLK) void adds_main(
    const float* __restrict__ pred_R, const float* __restrict__ pred_t,
    const float* __restrict__ gt_R,   const float* __restrict__ gt_t,
    const float* __restrict__ mp,     unsigned* __restrict__ dmin)
{
    __shared__ float4 g4[GTN];          // 8 KB

    const int b   = blockIdx.x & 15;
    const int pch = (blockIdx.x >> 4) & (PCH - 1);
    const int gtq = blockIdx.x >> 6;
    const int tid = threadIdx.x;

    // ---- stage gt partition into LDS (transform fused) ----
    float gR[9];
#pragma unroll
    for (int i = 0; i < 9; ++i) gR[i] = gt_R[b * 9 + i];
    const float gtx = gt_t[b * 3 + 0];
    const float gty = gt_t[b * 3 + 1];
    const float gtz = gt_t[b * 3 + 2];

#pragma unroll
    for (int k = 0; k < GTN / BLK; ++k) {
        const int nl = k * BLK + tid;
        const int n  = gtq * GTN + nl;
        const float mx = mp[n * 3 + 0];
        const float my = mp[n * 3 + 1];
        const float mz = mp[n * 3 + 2];
        const float gx = fmaf(gR[0], mx, fmaf(gR[1], my, fmaf(gR[2], mz, gtx)));
        const float gy = fmaf(gR[3], mx, fmaf(gR[4], my, fmaf(gR[5], mz, gty)));
        const float gz = fmaf(gR[6], mx, fmaf(gR[7], my, fmaf(gR[8], mz, gtz)));
        const float gn = fmaf(gx, gx, fmaf(gy, gy, gz * gz));
        g4[nl] = make_float4(-2.0f * gx, -2.0f * gy, -2.0f * gz, gn);
    }

    // ---- this thread's P pred points ----
    float pR[9];
#pragma unroll
    for (int i = 0; i < 9; ++i) pR[i] = pred_R[b * 9 + i];
    const float ptx = pred_t[b * 3 + 0];
    const float pty = pred_t[b * 3 + 1];
    const float ptz = pred_t[b * 3 + 2];

    float px[P], py[P], pz[P], pn[P];
#pragma unroll
    for (int p = 0; p < P; ++p) {
        const int m = pch * PREDS_PER_BLK + p * BLK + tid;  // coalesced per p
        const float mx = mp[m * 3 + 0];
        const float my = mp[m * 3 + 1];
        const float mz = mp[m * 3 + 2];
        px[p] = fmaf(pR[0], mx, fmaf(pR[1], my, fmaf(pR[2], mz, ptx)));
        py[p] = fmaf(pR[3], mx, fmaf(pR[4], my, fmaf(pR[5], mz, pty)));
        pz[p] = fmaf(pR[6], mx, fmaf(pR[7], my, fmaf(pR[8], mz, ptz)));
        pn[p] = fmaf(px[p], px[p], fmaf(py[p], py[p], pz[p] * pz[p]));
    }

    __syncthreads();

    // ---- min over partition: per 4 gt points, 4 ds_read feed 16 chains ----
    float best0[P], best1[P];
#pragma unroll
    for (int p = 0; p < P; ++p) { best0[p] = FLT_MAX; best1[p] = FLT_MAX; }

    for (int n = 0; n < GTN; n += 4) {
        const float4 h0 = g4[n + 0];
        const float4 h1 = g4[n + 1];
        const float4 h2 = g4[n + 2];
        const float4 h3 = g4[n + 3];
#pragma unroll
        for (int p = 0; p < P; ++p) {
            const float s0 = fmaf(h0.x, px[p], fmaf(h0.y, py[p], fmaf(h0.z, pz[p], h0.w)));
            const float s1 = fmaf(h1.x, px[p], fmaf(h1.y, py[p], fmaf(h1.z, pz[p], h1.w)));
            const float s2 = fmaf(h2.x, px[p], fmaf(h2.y, py[p], fmaf(h2.z, pz[p], h2.w)));
            const float s3 = fmaf(h3.x, px[p], fmaf(h3.y, py[p], fmaf(h3.z, pz[p], h3.w)));
            best0[p] = fminf(best0[p], fminf(s0, s1));   // -> v_min3_f32
            best1[p] = fminf(best1[p], fminf(s2, s3));   // -> v_min3_f32
        }
    }

#pragma unroll
    for (int p = 0; p < P; ++p) {
        const float smin = fminf(best0[p], best1[p]);
        const float d2 = fmaxf(pn[p] + smin, 0.0f);
        const int m = pch * PREDS_PER_BLK + p * BLK + tid;
        atomicMin(&dmin[b * MPTS + m], __float_as_uint(d2));
    }
}

// Kernel 3a: 65536 mins -> sqrt -> 64 block partial sums.
__global__ __launch_bounds__(1024) void adds_finish1(
    const unsigned* __restrict__ dmin, float* __restrict__ partial)
{
    __shared__ float wsum[16];
    const int tid = threadIdx.x;
    const float v = sqrtf(__uint_as_float(dmin[blockIdx.x * 1024 + tid]));
    float s = v;
#pragma unroll
    for (int off = 32; off > 0; off >>= 1) s += __shfl_down(s, off, 64);
    if ((tid & 63) == 0) wsum[tid >> 6] = s;
    __syncthreads();
    if (tid == 0) {
        float t = 0.0f;
#pragma unroll
        for (int w = 0; w < 16; ++w) t += wsum[w];
        partial[blockIdx.x] = t;
    }
}

// Kernel 3b: 64 partials -> mean.
__global__ __launch_bounds__(64) void adds_finish2(
    const float* __restrict__ partial, float* __restrict__ out)
{
    float s = partial[threadIdx.x];
#pragma unroll
    for (int off = 32; off > 0; off >>= 1) s += __shfl_down(s, off, 64);
    if (threadIdx.x == 0) out[0] = s * (1.0f / (float)NPRED);
}

extern "C" void kernel_launch(void* const* d_in, const int* in_sizes, int n_in,
                              void* d_out, int out_size, void* d_ws, size_t ws_size,
                              hipStream_t stream) {
    const float* pred_R = (const float*)d_in[0];
    const float* pred_t = (const float*)d_in[1];
    const float* gt_R   = (const float*)d_in[2];
    const float* gt_t   = (const float*)d_in[3];
    const float* mp     = (const float*)d_in[4];
    float* out = (float*)d_out;
    unsigned* dmin = (unsigned*)d_ws;             // 256 KB
    float* partial = (float*)((char*)d_ws + NPRED * sizeof(unsigned)); // 64 floats

    adds_init<<<dim3(NPRED / 1024), dim3(1024), 0, stream>>>(dmin);
    adds_main<<<dim3(NB * PCH * GTQ), dim3(BLK), 0, stream>>>(
        pred_R, pred_t, gt_R, gt_t, mp, dmin);
    adds_finish1<<<dim3(64), dim3(1024), 0, stream>>>(dmin, partial);
    adds_finish2<<<dim3(1), dim3(64), 0, stream>>>(partial, out);
}

// Round 4
// 31.143 us; speedup vs baseline: 3.3854x; 1.1093x over previous
//
#include <hip/hip_runtime.h>
#include <hip/hip_bf16.h>
#include <float.h>

// Problem constants: B=16, M=4096.
#define NB 16
#define MPTS 4096
#define NPRED (NB * MPTS)          // 65536 pred points
#define GTQ 16                     // gt partitions (occupancy lever)
#define GTN (MPTS / GTQ)           // 256 gt points per block
#define P 4                        // pred points per thread
#define BLK 256
#define PREDS_PER_BLK (BLK * P)    // 1024
#define PCH (MPTS / PREDS_PER_BLK) // 4 pred chunks per batch
#define GUNROLL 8

// Kernel 1: one block = (batch b, 1024-pred chunk, gt 16th).
// LDS: (-2gx,-2gy,-2gz,||g||^2) float4 per gt point (4 KB).
// Each thread owns P=4 pred points; 8 gt points per iter -> each
// ds_read_b128 feeds 4 fma-chains; writes partial min d2 (no atomics,
// every slot written every call -> deterministic, no init pass).
__global__ __launch_bounds__(BLK) void adds_main(
    const float* __restrict__ pred_R, const float* __restrict__ pred_t,
    const float* __restrict__ gt_R,   const float* __restrict__ gt_t,
    const float* __restrict__ mp,     float* __restrict__ pmin)
{
    __shared__ float4 g4[GTN];          // 4 KB

    const int b   = blockIdx.x & 15;
    const int pch = (blockIdx.x >> 4) & (PCH - 1);
    const int gtq = blockIdx.x >> 6;
    const int tid = threadIdx.x;

    // ---- stage gt partition into LDS (transform fused) ----
    float gR[9];
#pragma unroll
    for (int i = 0; i < 9; ++i) gR[i] = gt_R[b * 9 + i];
    const float gtx = gt_t[b * 3 + 0];
    const float gty = gt_t[b * 3 + 1];
    const float gtz = gt_t[b * 3 + 2];

    {
        const int nl = tid;                 // GTN == BLK
        const int n  = gtq * GTN + nl;
        const float mx = mp[n * 3 + 0];
        const float my = mp[n * 3 + 1];
        const float mz = mp[n * 3 + 2];
        const float gx = fmaf(gR[0], mx, fmaf(gR[1], my, fmaf(gR[2], mz, gtx)));
        const float gy = fmaf(gR[3], mx, fmaf(gR[4], my, fmaf(gR[5], mz, gty)));
        const float gz = fmaf(gR[6], mx, fmaf(gR[7], my, fmaf(gR[8], mz, gtz)));
        const float gn = fmaf(gx, gx, fmaf(gy, gy, gz * gz));
        g4[nl] = make_float4(-2.0f * gx, -2.0f * gy, -2.0f * gz, gn);
    }

    // ---- this thread's P pred points ----
    float pR[9];
#pragma unroll
    for (int i = 0; i < 9; ++i) pR[i] = pred_R[b * 9 + i];
    const float ptx = pred_t[b * 3 + 0];
    const float pty = pred_t[b * 3 + 1];
    const float ptz = pred_t[b * 3 + 2];

    float px[P], py[P], pz[P], pn[P];
#pragma unroll
    for (int p = 0; p < P; ++p) {
        const int m = pch * PREDS_PER_BLK + p * BLK + tid;  // coalesced per p
        const float mx = mp[m * 3 + 0];
        const float my = mp[m * 3 + 1];
        const float mz = mp[m * 3 + 2];
        px[p] = fmaf(pR[0], mx, fmaf(pR[1], my, fmaf(pR[2], mz, ptx)));
        py[p] = fmaf(pR[3], mx, fmaf(pR[4], my, fmaf(pR[5], mz, pty)));
        pz[p] = fmaf(pR[6], mx, fmaf(pR[7], my, fmaf(pR[8], mz, ptz)));
        pn[p] = fmaf(px[p], px[p], fmaf(py[p], py[p], pz[p] * pz[p]));
    }

    __syncthreads();

    // ---- min over partition: 8 gt points/iter, 32 pairs/iter ----
    float best0[P], best1[P];
#pragma unroll
    for (int p = 0; p < P; ++p) { best0[p] = FLT_MAX; best1[p] = FLT_MAX; }

    for (int n = 0; n < GTN; n += GUNROLL) {
        float4 h[GUNROLL];
#pragma unroll
        for (int u = 0; u < GUNROLL; ++u) h[u] = g4[n + u];
#pragma unroll
        for (int p = 0; p < P; ++p) {
            float s[GUNROLL];
#pragma unroll
            for (int u = 0; u < GUNROLL; ++u)
                s[u] = fmaf(h[u].x, px[p], fmaf(h[u].y, py[p], fmaf(h[u].z, pz[p], h[u].w)));
            best0[p] = fminf(best0[p], fminf(s[0], s[1]));   // v_min3_f32
            best1[p] = fminf(best1[p], fminf(s[2], s[3]));
            best0[p] = fminf(best0[p], fminf(s[4], s[5]));
            best1[p] = fminf(best1[p], fminf(s[6], s[7]));
        }
    }

#pragma unroll
    for (int p = 0; p < P; ++p) {
        const float smin = fminf(best0[p], best1[p]);
        const float d2 = fmaxf(pn[p] + smin, 0.0f);
        const int m = pch * PREDS_PER_BLK + p * BLK + tid;
        pmin[gtq * NPRED + b * MPTS + m] = d2;   // coalesced
    }
}

// Kernel 2: per pred point, min over the 16 partials -> sqrt -> block sums.
__global__ __launch_bounds__(1024) void adds_finish1(
    const float* __restrict__ pmin, float* __restrict__ partial)
{
    __shared__ float wsum[16];
    const int tid = threadIdx.x;
    const int g = blockIdx.x * 1024 + tid;
    float m0 = FLT_MAX, m1 = FLT_MAX;
#pragma unroll
    for (int q = 0; q < GTQ; q += 2) {
        m0 = fminf(m0, pmin[(q + 0) * NPRED + g]);
        m1 = fminf(m1, pmin[(q + 1) * NPRED + g]);
    }
    float s = sqrtf(fminf(m0, m1));
#pragma unroll
    for (int off = 32; off > 0; off >>= 1) s += __shfl_down(s, off, 64);
    if ((tid & 63) == 0) wsum[tid >> 6] = s;
    __syncthreads();
    if (tid == 0) {
        float t = 0.0f;
#pragma unroll
        for (int w = 0; w < 16; ++w) t += wsum[w];
        partial[blockIdx.x] = t;
    }
}

// Kernel 3: 64 partials -> mean.
__global__ __launch_bounds__(64) void adds_finish2(
    const float* __restrict__ partial, float* __restrict__ out)
{
    float s = partial[threadIdx.x];
#pragma unroll
    for (int off = 32; off > 0; off >>= 1) s += __shfl_down(s, off, 64);
    if (threadIdx.x == 0) out[0] = s * (1.0f / (float)NPRED);
}

extern "C" void kernel_launch(void* const* d_in, const int* in_sizes, int n_in,
                              void* d_out, int out_size, void* d_ws, size_t ws_size,
                              hipStream_t stream) {
    const float* pred_R = (const float*)d_in[0];
    const float* pred_t = (const float*)d_in[1];
    const float* gt_R   = (const float*)d_in[2];
    const float* gt_t   = (const float*)d_in[3];
    const float* mp     = (const float*)d_in[4];
    float* out = (float*)d_out;
    float* pmin = (float*)d_ws;                                   // 16*64K*4 = 4 MB
    float* partial = (float*)((char*)d_ws + GTQ * NPRED * sizeof(float)); // 64 floats

    adds_main<<<dim3(NB * PCH * GTQ), dim3(BLK), 0, stream>>>(
        pred_R, pred_t, gt_R, gt_t, mp, pmin);
    adds_finish1<<<dim3(64), dim3(1024), 0, stream>>>(pmin, partial);
    adds_finish2<<<dim3(1), dim3(64), 0, stream>>>(partial, out);
}